// Round 12
// baseline (4521.508 us; speedup 1.0000x reference)
//
#include <hip/hip_runtime.h>
#include <math.h>

#define HW 65536

typedef unsigned short ushortt;
typedef __attribute__((ext_vector_type(8))) short short8;
typedef __attribute__((ext_vector_type(16))) float floatx16;

__device__ __forceinline__ int refl(int i) {
    return i < 0 ? -i : (i > 255 ? 510 - i : i);
}

__device__ __forceinline__ ushortt f2bf(float f) {
    unsigned u = __builtin_bit_cast(unsigned, f);
    u += 0x7fffu + ((u >> 16) & 1u);   // RNE
    return (ushortt)(u >> 16);
}

__device__ __forceinline__ float bf2f(ushortt u) {
    unsigned x = ((unsigned)u) << 16;
    return __builtin_bit_cast(float, x);
}

__device__ __forceinline__ float bf2f_s(short u) {
    unsigned x = ((unsigned)(ushortt)u) << 16;
    return __builtin_bit_cast(float, x);
}

// ---- init: w1 passthrough + zero loss slot ----
__global__ __launch_bounds__(256) void k_init(const float* __restrict__ w1, float* __restrict__ out) {
    int idx = blockIdx.x * 256 + threadIdx.x;
    if (idx < 14641) out[131072 + idx] = w1[idx];
    if (idx == 14641) out[145713] = 0.f;
}

// ---- Wx1 = conv11x11 (Cin=1 -> 121), reflect pad, bf16 out ----
__global__ __launch_bounds__(256) void k_conv11_1toC(const float* __restrict__ in,
                                                     const float* __restrict__ w,
                                                     const float* __restrict__ bias,
                                                     ushortt* __restrict__ out) {
    int p = blockIdx.x * 256 + threadIdx.x;
    int oc = blockIdx.y, b = blockIdx.z;
    int y = p >> 8, x = p & 255;
    float acc = bias[oc];
    const float* wr = w + oc * 121;
    for (int ky = 0; ky < 11; ++ky) {
        int ry = refl(y + ky - 5);
        const float* irow = in + b * HW + (ry << 8);
        #pragma unroll
        for (int kx = 0; kx < 11; ++kx) {
            int rx = refl(x + kx - 5);
            acc += wr[ky * 11 + kx] * irow[rx];
        }
    }
    out[((b * 121 + oc) << 16) + p] = f2bf(acc);
}

// ---- weight repack (11x11): NEW layout Wfrag[kc][s][mt][lane][j] bf16 (L2-friendly chunks) ----
__global__ __launch_bounds__(256) void k_wrepack(const float* __restrict__ w, int transposed,
                                                 short* __restrict__ outw) {
    int idx = blockIdx.x * 256 + threadIdx.x;
    if (idx >= 1982464) return;   // 121 << 14
    int j    = idx & 7;
    int lane = (idx >> 3) & 63;
    int mt   = (idx >> 9) & 3;
    int kc   = (idx >> 11) & 7;
    int s    = idx >> 14;
    int oc = mt * 32 + (lane & 31);
    int ic = kc * 16 + (lane >> 5) * 8 + j;
    int ky = s / 11, kx = s - ky * 11;
    float v = 0.f;
    if (oc < 121 && ic < 121)
        v = transposed ? w[((ic * 121 + oc) * 11 + (10 - ky)) * 11 + (10 - kx)]
                       : w[((oc * 121 + ic) * 11 + ky) * 11 + kx];
    int out_off = ((((kc * 121 + s) * 4 + mt) * 64 + lane) << 3) + j;
    outw[out_off] = (short)f2bf(v);
}

// ---- weight repack (3x3, 122 ic) ----
__global__ __launch_bounds__(256) void k_wrepack3(const float* __restrict__ w,
                                                  short* __restrict__ outw) {
    int idx = blockIdx.x * 256 + threadIdx.x;
    if (idx >= 147456) return;    // 9 << 14
    int j    = idx & 7;
    int lane = (idx >> 3) & 63;
    int mt   = (idx >> 9) & 3;
    int kc   = (idx >> 11) & 7;
    int s    = idx >> 14;
    int oc = mt * 32 + (lane & 31);
    int ic = kc * 16 + (lane >> 5) * 8 + j;
    float v = 0.f;
    if (oc < 121 && ic < 122)
        v = w[(oc * 122 + ic) * 9 + s];
    outw[idx] = (short)f2bf(v);
}

// ---- weight repack thw ----
__global__ __launch_bounds__(256) void k_wrepack_thw(const float* __restrict__ thw,
                                                     short* __restrict__ outw) {
    int idx = blockIdx.x * 256 + threadIdx.x;
    if (idx >= 126976) return;    // 31*8*64*8
    int j    = idx & 7;
    int lane = (idx >> 3) & 63;
    int kc   = (idx >> 9) & 7;
    int g    = idx >> 12;
    int m = lane & 31, kg = lane >> 5;
    int k = kc * 16 + kg * 8 + j;
    int sel = m >> 3, mc = m & 7;
    int ch = g * 8 + mc;
    float v = 0.f;
    if (sel < 3 && ch < 244 && k < 122)
        v = thw[(sel * 244 + ch) * 122 + k];
    outw[idx] = (short)f2bf(v);
}

#define ADV11(cb, kx) { if (kx == 10) { kx = 0; cb += 384; } else { ++kx; cb += 24; } }
#define LOADSLOT(W0, W1, W2, W3, V0, V1) { \
    W0 = wp[0]; W1 = wp[64]; W2 = wp[128]; W3 = wp[192]; \
    V0 = *(const short8*)&lt[cb]; V1 = *(const short8*)&lt[cb + 1248]; }
#define MFMA8(W0, W1, W2, W3, V0, V1) { \
    acc[0] = __builtin_amdgcn_mfma_f32_32x32x16_bf16(W0, V0, acc[0], 0, 0, 0); \
    acc[1] = __builtin_amdgcn_mfma_f32_32x32x16_bf16(W0, V1, acc[1], 0, 0, 0); \
    acc[2] = __builtin_amdgcn_mfma_f32_32x32x16_bf16(W1, V0, acc[2], 0, 0, 0); \
    acc[3] = __builtin_amdgcn_mfma_f32_32x32x16_bf16(W1, V1, acc[3], 0, 0, 0); \
    acc[4] = __builtin_amdgcn_mfma_f32_32x32x16_bf16(W2, V0, acc[4], 0, 0, 0); \
    acc[5] = __builtin_amdgcn_mfma_f32_32x32x16_bf16(W2, V1, acc[5], 0, 0, 0); \
    acc[6] = __builtin_amdgcn_mfma_f32_32x32x16_bf16(W3, V0, acc[6], 0, 0, 0); \
    acc[7] = __builtin_amdgcn_mfma_f32_32x32x16_bf16(W3, V1, acc[7], 0, 0, 0); }

// ---- MFMA 11x11 conv 121->121 v6: v5 pipeline + kc-major Wfrag + vectorized staging ----
__global__ __launch_bounds__(256, 2) void k_conv11_mfma(const ushortt* __restrict__ in,
                                                        const short* __restrict__ Wf,
                                                        const float* __restrict__ bias,
                                                        float scale,
                                                        const ushortt* __restrict__ cmp,
                                                        ushortt* __restrict__ out,
                                                        float* __restrict__ lossout) {
    __shared__ __align__(16) ushortt lt[26 * 26 * 24];   // 32,448 B
    int tid = threadIdx.x;
    int lane = tid & 63, wv = tid >> 6;
    int l15 = lane & 15, sub = (lane >> 4) & 1, kg = lane >> 5;
    int bx = blockIdx.x, b = blockIdx.y;
    int y0 = (bx >> 4) * 16, x0 = (bx & 15) * 16;
    bool interior = (y0 != 0) && (y0 != 240) && (x0 != 0) && (x0 != 240);

    floatx16 acc[8];
    #pragma unroll
    for (int i = 0; i < 8; ++i)
        #pragma unroll
        for (int e = 0; e < 16; ++e) acc[i][e] = 0.f;

    const short8* Wf8 = (const short8*)Wf;
    for (int kc = 0; kc < 8; ++kc) {
        __syncthreads();
        if (interior) {
            // fast path: aligned short8 global loads + predicated b16 LDS scatter
            for (int pi = tid; pi < 416; pi += 256) {        // 16 ic x 26 rows
                int ic = pi / 26, r = pi - ic * 26;
                int gic = kc * 16 + ic;
                ushortt* dst = &lt[r * 26 * 24 + ic];
                if (gic < 121) {
                    const ushortt* src = in + ((b * 121 + gic) << 16) + ((y0 + r - 5) << 8) + x0 - 8;
                    #pragma unroll
                    for (int sg = 0; sg < 4; ++sg) {
                        short8 v = *(const short8*)&src[sg * 8];
                        #pragma unroll
                        for (int q = 0; q < 8; ++q) {
                            int c = sg * 8 + q - 3;
                            if ((unsigned)c < 26u) dst[c * 24] = (ushortt)v[q];
                        }
                    }
                } else {
                    #pragma unroll
                    for (int c = 0; c < 26; ++c) dst[c * 24] = 0;
                }
            }
        } else {
            for (int idx = tid; idx < 26 * 26 * 16; idx += 256) {
                int ic = idx / 676, pix = idx - ic * 676;
                int r = pix / 26, c = pix - r * 26;
                int gic = kc * 16 + ic;
                ushortt v = 0;
                if (gic < 121) {
                    int gy = refl(y0 + r - 5), gx = refl(x0 + c - 5);
                    v = in[((b * 121 + gic) << 16) + (gy << 8) + gx];
                }
                lt[pix * 24 + ic] = v;
            }
        }
        __syncthreads();
        const short8* wp = Wf8 + (kc * 121) * 256 + lane;
        int cb = ((4 * wv + sub) * 26 + l15) * 24 + kg * 8;
        int kx = 0;
        short8 A0, A1, A2, A3, Ab0, Ab1;
        short8 B0, B1, B2, B3, Bb0, Bb1;
        short8 C0, C1, C2, C3, Cb0, Cb1;
        LOADSLOT(A0, A1, A2, A3, Ab0, Ab1);               // s=0
        wp += 256; ADV11(cb, kx);
        LOADSLOT(B0, B1, B2, B3, Bb0, Bb1);               // s=1
        #pragma unroll 1
        for (int it = 0; it < 39; ++it) {
            wp += 256; ADV11(cb, kx);
            LOADSLOT(C0, C1, C2, C3, Cb0, Cb1);           // s=3it+2
            MFMA8(A0, A1, A2, A3, Ab0, Ab1);              // s=3it
            wp += 256; ADV11(cb, kx);
            LOADSLOT(A0, A1, A2, A3, Ab0, Ab1);           // s=3it+3
            MFMA8(B0, B1, B2, B3, Bb0, Bb1);              // s=3it+1
            wp += 256; ADV11(cb, kx);
            LOADSLOT(B0, B1, B2, B3, Bb0, Bb1);           // s=3it+4
            MFMA8(C0, C1, C2, C3, Cb0, Cb1);              // s=3it+2
        }
        wp += 256; ADV11(cb, kx);
        LOADSLOT(C0, C1, C2, C3, Cb0, Cb1);               // s=119
        MFMA8(A0, A1, A2, A3, Ab0, Ab1);                  // 117
        wp += 256; ADV11(cb, kx);
        LOADSLOT(A0, A1, A2, A3, Ab0, Ab1);               // s=120
        MFMA8(B0, B1, B2, B3, Bb0, Bb1);                  // 118
        MFMA8(C0, C1, C2, C3, Cb0, Cb1);                  // 119
        MFMA8(A0, A1, A2, A3, Ab0, Ab1);                  // 120
    }
    if (!cmp) {
        #pragma unroll
        for (int mt = 0; mt < 4; ++mt) {
            #pragma unroll
            for (int e = 0; e < 16; ++e) {
                int oc = mt * 32 + (e & 3) + 8 * (e >> 2) + 4 * kg;
                if (oc < 121) {
                    float bv = bias ? bias[oc] : 0.f;
                    #pragma unroll
                    for (int t = 0; t < 2; ++t) {
                        int y = y0 + 4 * wv + 2 * t + sub, x = x0 + l15;
                        out[((b * 121 + oc) << 16) + (y << 8) + x] = f2bf((acc[mt * 2 + t][e] + bv) * scale);
                    }
                }
            }
        }
    } else {
        float lsum = 0.f;
        #pragma unroll
        for (int mt = 0; mt < 4; ++mt) {
            #pragma unroll
            for (int e = 0; e < 16; ++e) {
                int oc = mt * 32 + (e & 3) + 8 * (e >> 2) + 4 * kg;
                if (oc < 121) {
                    float bv = bias ? bias[oc] : 0.f;
                    #pragma unroll
                    for (int t = 0; t < 2; ++t) {
                        int y = y0 + 4 * wv + 2 * t + sub, x = x0 + l15;
                        float res = (acc[mt * 2 + t][e] + bv) * scale;
                        float df = res - bf2f(cmp[((b * 121 + oc) << 16) + (y << 8) + x]);
                        lsum += df * df;
                    }
                }
            }
        }
        __syncthreads();
        float* red = (float*)lt;
        red[tid] = lsum;
        __syncthreads();
        for (int off = 128; off > 0; off >>= 1) {
            if (tid < off) red[tid] += red[tid + off];
            __syncthreads();
        }
        if (tid == 0) atomicAdd(lossout, red[0]);
    }
}

// ---- MFMA 3x3 conv 122->121, bf16 in/out, zero pad, sey folded, clip ----
__global__ __launch_bounds__(256, 2) void k_conv3_mfma(const ushortt* __restrict__ in,
                                                       const short* __restrict__ Wf,
                                                       const float* __restrict__ bias,
                                                       const float* __restrict__ sey,
                                                       ushortt* __restrict__ out) {
    __shared__ __align__(16) ushortt lt[18 * 18 * 24];
    int tid = threadIdx.x;
    int lane = tid & 63, wv = tid >> 6;
    int l15 = lane & 15, sub = (lane >> 4) & 1, kg = lane >> 5;
    int bx = blockIdx.x, b = blockIdx.y;
    int y0 = (bx >> 4) * 16, x0 = (bx & 15) * 16;

    floatx16 acc[8];
    #pragma unroll
    for (int i = 0; i < 8; ++i)
        #pragma unroll
        for (int e = 0; e < 16; ++e) acc[i][e] = 0.f;

    const short8* Wf8 = (const short8*)Wf;
    for (int kc = 0; kc < 8; ++kc) {
        __syncthreads();
        for (int idx = tid; idx < 18 * 18 * 16; idx += 256) {
            int ic = idx / 324, pix = idx - ic * 324;
            int r = pix / 18, c = pix - r * 18;
            int gic = kc * 16 + ic;
            float v = 0.f;
            if (gic < 122) {
                int gy = y0 + r - 1, gx = x0 + c - 1;
                if ((unsigned)gy < 256u && (unsigned)gx < 256u)
                    v = bf2f(in[((b * 122 + gic) << 16) + (gy << 8) + gx]) * sey[b * 122 + gic];
            }
            lt[pix * 24 + ic] = f2bf(v);
        }
        __syncthreads();
        const short8* wp = Wf8 + kc * 256 + lane;
        int cb = ((4 * wv + sub) * 18 + l15) * 24 + kg * 8;
        short8 a0 = wp[0], a1 = wp[64], a2 = wp[128], a3 = wp[192];
        short8 b0 = *(const short8*)&lt[cb];
        short8 b1 = *(const short8*)&lt[cb + 864];
        int kx = 0;
        #pragma unroll 1
        for (int s = 0; s < 9; ++s) {
            short8 na0 = a0, na1 = a1, na2 = a2, na3 = a3, nb0 = b0, nb1 = b1;
            if (s < 8) {
                wp += 2048;
                if (kx == 2) { kx = 0; cb += 384; }
                else         { ++kx;  cb += 24;  }
                na0 = wp[0]; na1 = wp[64]; na2 = wp[128]; na3 = wp[192];
                nb0 = *(const short8*)&lt[cb];
                nb1 = *(const short8*)&lt[cb + 864];
            }
            acc[0] = __builtin_amdgcn_mfma_f32_32x32x16_bf16(a0, b0, acc[0], 0, 0, 0);
            acc[1] = __builtin_amdgcn_mfma_f32_32x32x16_bf16(a0, b1, acc[1], 0, 0, 0);
            acc[2] = __builtin_amdgcn_mfma_f32_32x32x16_bf16(a1, b0, acc[2], 0, 0, 0);
            acc[3] = __builtin_amdgcn_mfma_f32_32x32x16_bf16(a1, b1, acc[3], 0, 0, 0);
            acc[4] = __builtin_amdgcn_mfma_f32_32x32x16_bf16(a2, b0, acc[4], 0, 0, 0);
            acc[5] = __builtin_amdgcn_mfma_f32_32x32x16_bf16(a2, b1, acc[5], 0, 0, 0);
            acc[6] = __builtin_amdgcn_mfma_f32_32x32x16_bf16(a3, b0, acc[6], 0, 0, 0);
            acc[7] = __builtin_amdgcn_mfma_f32_32x32x16_bf16(a3, b1, acc[7], 0, 0, 0);
            a0 = na0; a1 = na1; a2 = na2; a3 = na3; b0 = nb0; b1 = nb1;
        }
    }
    #pragma unroll
    for (int mt = 0; mt < 4; ++mt) {
        #pragma unroll
        for (int e = 0; e < 16; ++e) {
            int oc = mt * 32 + (e & 3) + 8 * (e >> 2) + 4 * kg;
            if (oc < 121) {
                float bv = bias[oc];
                #pragma unroll
                for (int t = 0; t < 2; ++t) {
                    int y = y0 + 4 * wv + 2 * t + sub, x = x0 + l15;
                    float res = fminf(fmaxf(acc[mt * 2 + t][e] + bv, 0.f), 10.f);
                    out[((b * 121 + oc) << 16) + (y << 8) + x] = f2bf(res);
                }
            }
        }
    }
}

// ---- FSAS: per 8x8 patch, MFMA 1x1 conv + VALU depthwise/circular; Wx bf16 ----
__global__ __launch_bounds__(256, 3) void k_fsas_patch(const float* __restrict__ input,
                                                       const ushortt* __restrict__ Wx,
                                                       const float* __restrict__ n1w,
                                                       const float* __restrict__ n1b,
                                                       const short* __restrict__ thwf,
                                                       const float* __restrict__ tdw,
                                                       ushortt* __restrict__ o_out,
                                                       ushortt* __restrict__ v_out) {
    __shared__ __align__(16) ushortt xnb[100 * 136];
    __shared__ __align__(16) float h_lds[24 * 100];
    __shared__ __align__(16) float qb[8 * 64];
    __shared__ __align__(16) float kbd[8 * 8 * 20];
    int patch = blockIdx.x, b = blockIdx.y;
    int py0 = (patch >> 5) << 3, px0 = (patch & 31) << 3;
    int tid = threadIdx.x;
    int lane = tid & 63, wvv = tid >> 6;
    int l31 = lane & 31, kg = lane >> 5;

    for (int idx = tid; idx < 12200; idx += 256) {
        int c = idx / 100, pos = idx - c * 100;
        int gy = py0 + pos / 10 - 1, gx = px0 + pos % 10 - 1;
        ushortt v = 0;
        if ((unsigned)gy < 256u && (unsigned)gx < 256u) {
            int pix = (gy << 8) + gx;
            v = (c == 0) ? f2bf(input[(b << 16) + pix]) : Wx[((b * 121 + c - 1) << 16) + pix];
        }
        xnb[pos * 136 + c] = v;
    }
    for (int idx = tid; idx < 600; idx += 256) {
        int pos = idx / 6, c = 122 + (idx - (idx / 6) * 6);
        xnb[pos * 136 + c] = 0;
    }
    __syncthreads();
    if (tid < 100) {
        int pos = tid;
        int gy = py0 + pos / 10 - 1, gx = px0 + pos % 10 - 1;
        if ((unsigned)gy < 256u && (unsigned)gx < 256u) {
            float s = 0.f, ss = 0.f;
            for (int c = 0; c < 122; ++c) { float v = bf2f(xnb[pos * 136 + c]); s += v; ss += v * v; }
            float mu = s * (1.f / 122.f);
            float rs = rsqrtf(fmaxf(ss * (1.f / 122.f) - mu * mu, 0.f) + 1e-5f);
            for (int c = 0; c < 122; ++c) {
                float v = (bf2f(xnb[pos * 136 + c]) - mu) * rs * n1w[c] + n1b[c];
                xnb[pos * 136 + c] = f2bf(v);
            }
        }
    }
    __syncthreads();

    int p = wvv * 32 + l31;
    int pe = p < 100 ? p : 0;
    short8 bfr[8];
    #pragma unroll
    for (int kc = 0; kc < 8; ++kc)
        bfr[kc] = *(const short8*)&xnb[pe * 136 + kc * 16 + kg * 8];

    const short8* Af = (const short8*)thwf;
    for (int g = 0; g < 31; ++g) {
        floatx16 acc;
        #pragma unroll
        for (int e = 0; e < 16; ++e) acc[e] = 0.f;
        #pragma unroll
        for (int kc = 0; kc < 8; ++kc) {
            short8 a = Af[(g * 8 + kc) * 64 + lane];
            acc = __builtin_amdgcn_mfma_f32_32x32x16_bf16(a, bfr[kc], acc, 0, 0, 0);
        }
        if (p < 100) {
            #pragma unroll
            for (int e = 0; e < 16; ++e) {
                int m = (e & 3) + 8 * (e >> 2) + 4 * kg;
                if (m < 24) h_lds[m * 100 + p] = acc[e];
            }
        }
        __syncthreads();
        for (int it = tid; it < 1536; it += 256) {
            int m = it >> 6, pp = it & 63;
            int sel = m >> 3, cl = m & 7;
            int ch = g * 8 + cl;
            int py = pp >> 3, px = pp & 7;
            float dv = 0.f;
            if (ch < 244) {
                const float* td = tdw + (sel * 244 + ch) * 9;
                const float* hrow = &h_lds[m * 100];
                #pragma unroll
                for (int dy = 0; dy < 3; ++dy)
                    #pragma unroll
                    for (int dx = 0; dx < 3; ++dx)
                        dv += td[dy * 3 + dx] * hrow[(py + dy) * 10 + px + dx];
            }
            if (sel == 0) qb[cl * 64 + pp] = dv;
            else if (sel == 1) {
                kbd[(cl * 8 + py) * 20 + px] = dv;
                kbd[(cl * 8 + py) * 20 + px + 8] = dv;
            } else if (ch < 244) {
                v_out[((b * 244 + ch) << 16) + ((py0 + py) << 8) + px0 + px] = f2bf(dv);
            }
        }
        __syncthreads();
        {
            int cl = tid >> 5, u = (tid >> 2) & 7, ih = tid & 3;
            float ov[8];
            #pragma unroll
            for (int v = 0; v < 8; ++v) ov[v] = 0.f;
            #pragma unroll
            for (int ii = 0; ii < 2; ++ii) {
                int i = ih * 2 + ii;
                const float* qr = &qb[cl * 64 + i * 8];
                float q[8];
                *(float4*)q       = *(const float4*)qr;
                *(float4*)(q + 4) = *(const float4*)(qr + 4);
                const float* kr = &kbd[(cl * 8 + ((u - i) & 7)) * 20];
                float kk[16];
                *(float4*)kk        = *(const float4*)kr;
                *(float4*)(kk + 4)  = *(const float4*)(kr + 4);
                *(float4*)(kk + 8)  = *(const float4*)(kr + 8);
                *(float4*)(kk + 12) = *(const float4*)(kr + 12);
                #pragma unroll
                for (int j = 0; j < 8; ++j)
                    #pragma unroll
                    for (int v = 0; v < 8; ++v)
                        ov[v] += q[j] * kk[v + 8 - j];
            }
            #pragma unroll
            for (int v = 0; v < 8; ++v) {
                ov[v] += __shfl_xor(ov[v], 1);
                ov[v] += __shfl_xor(ov[v], 2);
            }
            int ch = g * 8 + cl;
            if (ih == 0 && ch < 244) {
                uint4 pk;
                pk.x = (unsigned)f2bf(ov[0]) | ((unsigned)f2bf(ov[1]) << 16);
                pk.y = (unsigned)f2bf(ov[2]) | ((unsigned)f2bf(ov[3]) << 16);
                pk.z = (unsigned)f2bf(ov[4]) | ((unsigned)f2bf(ov[5]) << 16);
                pk.w = (unsigned)f2bf(ov[6]) | ((unsigned)f2bf(ov[7]) << 16);
                *(uint4*)&o_out[((size_t)((b * 244 + ch)) << 16) + ((py0 + u) << 8) + px0] = pk;
            }
        }
        __syncthreads();
    }
}

// ---- a = v * LN_c(o) (in place over v), 8 px/thread ----
__global__ __launch_bounds__(256) void k_a_ln(const ushortt* __restrict__ o,
                                              ushortt* __restrict__ v,
                                              const float* __restrict__ fnw,
                                              const float* __restrict__ fnb) {
    int t = blockIdx.x * 256 + threadIdx.x;
    int p8 = t * 8;
    int b = p8 >> 16, pix = p8 & 65535;
    float s[8], ss[8];
    #pragma unroll
    for (int q = 0; q < 8; ++q) { s[q] = 0.f; ss[q] = 0.f; }
    for (int c = 0; c < 244; ++c) {
        short8 o8 = *(const short8*)&o[((b * 244 + c) << 16) + pix];
        #pragma unroll
        for (int q = 0; q < 8; ++q) {
            float f = bf2f_s(o8[q]);
            s[q] += f; ss[q] += f * f;
        }
    }
    float mu[8], rs[8];
    #pragma unroll
    for (int q = 0; q < 8; ++q) {
        mu[q] = s[q] * (1.f / 244.f);
        rs[q] = rsqrtf(fmaxf(ss[q] * (1.f / 244.f) - mu[q] * mu[q], 0.f) + 1e-5f);
    }
    for (int c = 0; c < 244; ++c) {
        int base = ((b * 244 + c) << 16) + pix;
        short8 o8 = *(const short8*)&o[base];
        short8 v8 = *(const short8*)&v[base];
        float w = fnw[c], bb = fnb[c];
        short8 r8;
        #pragma unroll
        for (int q = 0; q < 8; ++q) {
            float tt = (bf2f_s(o8[q]) - mu[q]) * rs[q] * w + bb;
            r8[q] = (short)f2bf(bf2f_s(v8[q]) * tt);
        }
        *(short8*)&v[base] = r8;
    }
}

// ---- out1(bf16) = cat + pw(1x1) @ a ; 8 px x 8 oc/thread, pw in LDS; Wx bf16 ----
__global__ __launch_bounds__(256) void k_pw_res(const ushortt* __restrict__ a,
                                                const float* __restrict__ pw,
                                                const float* __restrict__ input,
                                                const ushortt* __restrict__ Wx,
                                                ushortt* __restrict__ out1) {
    __shared__ float pws[8 * 244];
    int g = blockIdx.y, b = blockIdx.z;
    int tid = threadIdx.x;
    for (int i = tid; i < 8 * 244; i += 256) {
        int j = i / 244, c = i - j * 244;
        int oc = g * 8 + j;
        pws[i] = (oc < 122) ? pw[oc * 244 + c] : 0.f;
    }
    __syncthreads();
    int p = (blockIdx.x * 256 + tid) * 8;
    float acc[8][8];
    #pragma unroll
    for (int j = 0; j < 8; ++j)
        #pragma unroll
        for (int q = 0; q < 8; ++q) acc[j][q] = 0.f;
    for (int c = 0; c < 244; ++c) {
        short8 a8 = *(const short8*)&a[((b * 244 + c) << 16) + p];
        float av[8];
        #pragma unroll
        for (int q = 0; q < 8; ++q) av[q] = bf2f_s(a8[q]);
        #pragma unroll
        for (int j = 0; j < 8; ++j) {
            float w = pws[j * 244 + c];
            #pragma unroll
            for (int q = 0; q < 8; ++q) acc[j][q] += w * av[q];
        }
    }
    #pragma unroll
    for (int j = 0; j < 8; ++j) {
        int oc = g * 8 + j;
        if (oc < 122) {
            float cat[8];
            if (oc == 0) {
                const float* src = input + (b << 16) + p;
                float4 c0 = *(const float4*)src;
                float4 c1 = *(const float4*)(src + 4);
                cat[0] = c0.x; cat[1] = c0.y; cat[2] = c0.z; cat[3] = c0.w;
                cat[4] = c1.x; cat[5] = c1.y; cat[6] = c1.z; cat[7] = c1.w;
            } else {
                short8 w8 = *(const short8*)&Wx[((b * 121 + oc - 1) << 16) + p];
                #pragma unroll
                for (int q = 0; q < 8; ++q) cat[q] = bf2f_s(w8[q]);
            }
            short8 r8;
            #pragma unroll
            for (int q = 0; q < 8; ++q) r8[q] = (short)f2bf(cat[q] + acc[j][q]);
            *(short8*)&out1[((b * 122 + oc) << 16) + p] = r8;
        }
    }
}

// ---- SE: channel means (bf16 input) ----
__global__ __launch_bounds__(256) void k_se_mean(const ushortt* __restrict__ x, float* __restrict__ mean) {
    int c = blockIdx.x, b = blockIdx.y;
    const ushortt* p = x + ((b * 122 + c) << 16);
    float s = 0.f;
    for (int i = threadIdx.x * 8; i < HW; i += 2048) {
        short8 v8 = *(const short8*)&p[i];
        #pragma unroll
        for (int q = 0; q < 8; ++q) s += bf2f_s(v8[q]);
    }
    __shared__ float red[256];
    red[threadIdx.x] = s;
    __syncthreads();
    for (int off = 128; off > 0; off >>= 1) {
        if (threadIdx.x < off) red[threadIdx.x] += red[threadIdx.x + off];
        __syncthreads();
    }
    if (threadIdx.x == 0) mean[b * 122 + c] = red[0] * (1.f / HW);
}

// ---- SE: fc -> relu -> fc -> sigmoid ----
__global__ __launch_bounds__(256) void k_se_fc(const float* __restrict__ mean,
                                               const float* __restrict__ f1,
                                               const float* __restrict__ f2,
                                               float* __restrict__ sey) {
    int b = blockIdx.x, tid = threadIdx.x;
    __shared__ float y1[7];
    if (tid < 7) {
        float s = 0.f;
        for (int c = 0; c < 122; ++c) s += f1[tid * 122 + c] * mean[b * 122 + c];
        y1[tid] = fmaxf(s, 0.f);
    }
    __syncthreads();
    if (tid < 122) {
        float s = 0.f;
        #pragma unroll
        for (int j = 0; j < 7; ++j) s += f2[tid * 7 + j] * y1[j];
        sey[b * 122 + tid] = 1.f / (1.f + expf(-s));
    }
}

// ---- z(bf16) = soft(Wx(bf16), c*sigma), 8 px/thread ----
__global__ __launch_bounds__(256) void k_soft(const ushortt* __restrict__ Wx,
                                              const ushortt* __restrict__ cbuf,
                                              const float* __restrict__ sigma,
                                              ushortt* __restrict__ z) {
    int idx = (blockIdx.x * 256 + threadIdx.x) * 8;
    int pix = idx & 65535;
    int b = (idx >> 16) / 121;
    short8 x8 = *(const short8*)&Wx[idx];
    short8 c8 = *(const short8*)&cbuf[idx];
    const float* sp = &sigma[(b << 16) + pix];
    float4 s0 = *(const float4*)sp;
    float4 s1 = *(const float4*)(sp + 4);
    float sv[8] = {s0.x, s0.y, s0.z, s0.w, s1.x, s1.y, s1.z, s1.w};
    short8 r8;
    #pragma unroll
    for (int q = 0; q < 8; ++q) {
        float t = bf2f_s(c8[q]) * sv[q];
        float x = bf2f_s(x8[q]);
        float r = x > t ? x - t : (x < -t ? x + t : 0.f);
        r8[q] = (short)f2bf(r);
    }
    *(short8*)&z[idx] = r8;
}

// ---- Wt = conv11(Wt2(bf16), rot180(w1)^T)/121, 121 -> 1; tile stride 48 ----
__global__ __launch_bounds__(256) void k_wt(const ushortt* __restrict__ Wt2,
                                            const float* __restrict__ w1,
                                            float* __restrict__ out) {
    __shared__ float tile[26 * 48];
    int b = blockIdx.y;
    int ty0 = (blockIdx.x >> 4) * 16, tx0 = (blockIdx.x & 15) * 16;
    int tid = threadIdx.x;
    int tX = tid & 15, tY = tid >> 4;
    float acc = 0.f;
    for (int ic = 0; ic < 121; ++ic) {
        const ushortt* src = Wt2 + ((b * 121 + ic) << 16);
        for (int idx = tid; idx < 26 * 26; idx += 256) {
            int r = idx / 26, c = idx - r * 26;
            tile[r * 48 + c] = bf2f(src[(refl(ty0 + r - 5) << 8) + refl(tx0 + c - 5)]);
        }
        __syncthreads();
        const float* wr = w1 + ic * 121;
        #pragma unroll 1
        for (int ky = 0; ky < 11; ++ky) {
            #pragma unroll
            for (int kx = 0; kx < 11; ++kx)
                acc += wr[(10 - ky) * 11 + (10 - kx)] * tile[(tY + ky) * 48 + tX + kx];
        }
        __syncthreads();
    }
    out[(b << 16) + ((ty0 + tY) << 8) + tx0 + tX] = acc * (1.f / 121.f);
}

extern "C" void kernel_launch(void* const* d_in, const int* in_sizes, int n_in,
                              void* d_out, int out_size, void* d_ws, size_t ws_size,
                              hipStream_t stream) {
    const float* input = (const float*)d_in[0];
    const float* sigma = (const float*)d_in[1];
    const float* w1    = (const float*)d_in[2];
    const float* b1    = (const float*)d_in[3];
    const float* w2    = (const float*)d_in[4];
    const float* b2    = (const float*)d_in[5];
    const float* n1w   = (const float*)d_in[6];
    const float* n1b   = (const float*)d_in[7];
    const float* thw   = (const float*)d_in[8];
    const float* tdw   = (const float*)d_in[9];
    const float* fnw   = (const float*)d_in[10];
    const float* fnb   = (const float*)d_in[11];
    const float* pw    = (const float*)d_in[12];
    const float* se1f1 = (const float*)d_in[13];
    const float* se1f2 = (const float*)d_in[14];
    const float* se2f1 = (const float*)d_in[15];
    const float* se2f2 = (const float*)d_in[16];
    const float* c1w   = (const float*)d_in[17];
    const float* c1b   = (const float*)d_in[18];
    const float* c2w   = (const float*)d_in[19];
    const float* c2b   = (const float*)d_in[20];
    float* out = (float*)d_out;
    float* ws  = (float*)d_ws;

    const size_t T121 = 15859712, T122 = 15990784;
    float* Wx1f   = ws;
    float* bufBf  = Wx1f + T121;
    float* C      = bufBf + T121;
    float* D      = C + T122;
    float* means  = D + T122;
    float* sey    = means + 256;
    short* thwf   = (short*)(sey + 256);
    ushortt* Wx1   = (ushortt*)Wx1f;
    ushortt* bufB  = (ushortt*)bufBf;
    ushortt* o_bf  = (ushortt*)C;
    ushortt* out1_bf = (ushortt*)C;
    ushortt* z_bf  = (ushortt*)C;
    ushortt* temp_bf = (ushortt*)C;
    ushortt* v_bf  = (ushortt*)D;
    ushortt* c_bf  = (ushortt*)D;
    short* WfA = (short*)D;
    short* WfB = (short*)(D + (1 << 20));
    short* Wf3 = (short*)(D + 9000000);

    dim3 blk(256);
    const ushortt* UNUL = nullptr;
    float* FNUL = nullptr;

    k_init<<<dim3(58), blk, 0, stream>>>(w1, out);
    k_wrepack_thw<<<dim3(496), blk, 0, stream>>>(thw, thwf);
    k_conv11_1toC<<<dim3(256, 121, 2), blk, 0, stream>>>(input, w1, b1, Wx1);

    // ---- tblock 1 ----
    k_fsas_patch<<<dim3(1024, 2), blk, 0, stream>>>(input, Wx1, n1w, n1b, thwf, tdw, o_bf, v_bf);
    k_a_ln<<<dim3(64), blk, 0, stream>>>(o_bf, v_bf, fnw, fnb);
    k_pw_res<<<dim3(32, 16, 2), blk, 0, stream>>>(v_bf, pw, input, Wx1, out1_bf);    // out1 -> C
    k_wrepack3<<<dim3(576), blk, 0, stream>>>(c1w, Wf3);
    k_se_mean<<<dim3(122, 2), blk, 0, stream>>>(out1_bf, means);
    k_se_fc<<<dim3(2), blk, 0, stream>>>(means, se1f1, se1f2, sey);
    k_conv3_mfma<<<dim3(256, 2), blk, 0, stream>>>(out1_bf, Wf3, c1b, sey, c_bf);    // c1 -> D
    k_soft<<<dim3(7744), blk, 0, stream>>>(Wx1, c_bf, sigma, z_bf);                  // z1 -> C
    k_wrepack<<<dim3(7744), blk, 0, stream>>>(w2, 0, WfA);
    k_conv11_mfma<<<dim3(256, 2), blk, 0, stream>>>(z_bf, WfA, b2, 1.f, UNUL, bufB, FNUL); // Wx2

    // ---- tblock 2 ----
    k_fsas_patch<<<dim3(1024, 2), blk, 0, stream>>>(input, bufB, n1w, n1b, thwf, tdw, o_bf, v_bf);
    k_a_ln<<<dim3(64), blk, 0, stream>>>(o_bf, v_bf, fnw, fnb);
    k_pw_res<<<dim3(32, 16, 2), blk, 0, stream>>>(v_bf, pw, input, bufB, out1_bf);
    k_wrepack3<<<dim3(576), blk, 0, stream>>>(c2w, Wf3);
    k_se_mean<<<dim3(122, 2), blk, 0, stream>>>(out1_bf, means);
    k_se_fc<<<dim3(2), blk, 0, stream>>>(means, se2f1, se2f2, sey);
    k_conv3_mfma<<<dim3(256, 2), blk, 0, stream>>>(out1_bf, Wf3, c2b, sey, c_bf);
    k_soft<<<dim3(7744), blk, 0, stream>>>(bufB, c_bf, sigma, z_bf);                 // z2 -> C

    // ---- tail ----
    k_wrepack<<<dim3(7744), blk, 0, stream>>>(w2, 0, WfA);
    k_wrepack<<<dim3(7744), blk, 0, stream>>>(w2, 1, WfB);
    k_conv11_mfma<<<dim3(256, 2), blk, 0, stream>>>(z_bf, WfB, FNUL, 1.f / 121.f, UNUL, bufB, FNUL); // Wt2
    k_wt<<<dim3(256, 2), blk, 0, stream>>>(bufB, w1, out);                                           // Wt
    k_conv11_mfma<<<dim3(256, 2), blk, 0, stream>>>(Wx1, WfA, b2, 1.f, UNUL, temp_bf, FNUL);         // temp
    k_conv11_mfma<<<dim3(256, 2), blk, 0, stream>>>(temp_bf, WfB, FNUL, 1.f / 121.f, Wx1, (ushortt*)FNUL, out + 145713); // W2loss

    (void)in_sizes; (void)n_in; (void)out_size; (void)ws_size;
}

// Round 13
// 4341.531 us; speedup vs baseline: 1.0415x; 1.0415x over previous
//
#include <hip/hip_runtime.h>
#include <math.h>

#define HW 65536

typedef unsigned short ushortt;
typedef __attribute__((ext_vector_type(8))) short short8;
typedef __attribute__((ext_vector_type(16))) float floatx16;

__device__ __forceinline__ int refl(int i) {
    return i < 0 ? -i : (i > 255 ? 510 - i : i);
}

__device__ __forceinline__ ushortt f2bf(float f) {
    unsigned u = __builtin_bit_cast(unsigned, f);
    u += 0x7fffu + ((u >> 16) & 1u);   // RNE
    return (ushortt)(u >> 16);
}

__device__ __forceinline__ float bf2f(ushortt u) {
    unsigned x = ((unsigned)u) << 16;
    return __builtin_bit_cast(float, x);
}

__device__ __forceinline__ float bf2f_s(short u) {
    unsigned x = ((unsigned)(ushortt)u) << 16;
    return __builtin_bit_cast(float, x);
}

// ---- init: w1 passthrough + zero loss slot ----
__global__ __launch_bounds__(256) void k_init(const float* __restrict__ w1, float* __restrict__ out) {
    int idx = blockIdx.x * 256 + threadIdx.x;
    if (idx < 14641) out[131072 + idx] = w1[idx];
    if (idx == 14641) out[145713] = 0.f;
}

// ---- Wx1 = conv11x11 (Cin=1 -> 121), reflect pad, bf16 out ----
__global__ __launch_bounds__(256) void k_conv11_1toC(const float* __restrict__ in,
                                                     const float* __restrict__ w,
                                                     const float* __restrict__ bias,
                                                     ushortt* __restrict__ out) {
    int p = blockIdx.x * 256 + threadIdx.x;
    int oc = blockIdx.y, b = blockIdx.z;
    int y = p >> 8, x = p & 255;
    float acc = bias[oc];
    const float* wr = w + oc * 121;
    for (int ky = 0; ky < 11; ++ky) {
        int ry = refl(y + ky - 5);
        const float* irow = in + b * HW + (ry << 8);
        #pragma unroll
        for (int kx = 0; kx < 11; ++kx) {
            int rx = refl(x + kx - 5);
            acc += wr[ky * 11 + kx] * irow[rx];
        }
    }
    out[((b * 121 + oc) << 16) + p] = f2bf(acc);
}

// ---- weight repack (11x11): Wfrag[kc][s(124, padded)][mt][lane][j] bf16 ----
__global__ __launch_bounds__(256) void k_wrepack(const float* __restrict__ w, int transposed,
                                                 short* __restrict__ outw) {
    int idx = blockIdx.x * 256 + threadIdx.x;
    if (idx >= 2031616) return;   // 8*124*4*64*8
    int j    = idx & 7;
    int lane = (idx >> 3) & 63;
    int mt   = (idx >> 9) & 3;
    int sk   = idx >> 11;         // kc*124 + s
    int kc   = sk / 124;
    int s    = sk - kc * 124;
    int oc = mt * 32 + (lane & 31);
    int ic = kc * 16 + (lane >> 5) * 8 + j;
    float v = 0.f;
    if (s < 121 && oc < 121 && ic < 121) {
        int ky = s / 11, kx = s - ky * 11;
        v = transposed ? w[((ic * 121 + oc) * 11 + (10 - ky)) * 11 + (10 - kx)]
                       : w[((oc * 121 + ic) * 11 + ky) * 11 + kx];
    }
    outw[idx] = (short)f2bf(v);
}

// ---- weight repack (3x3, 122 ic): Wfrag[s][kc][mt][lane][j] bf16 ----
__global__ __launch_bounds__(256) void k_wrepack3(const float* __restrict__ w,
                                                  short* __restrict__ outw) {
    int idx = blockIdx.x * 256 + threadIdx.x;
    if (idx >= 147456) return;    // 9 << 14
    int j    = idx & 7;
    int lane = (idx >> 3) & 63;
    int mt   = (idx >> 9) & 3;
    int kc   = (idx >> 11) & 7;
    int s    = idx >> 14;
    int oc = mt * 32 + (lane & 31);
    int ic = kc * 16 + (lane >> 5) * 8 + j;
    float v = 0.f;
    if (oc < 121 && ic < 122)
        v = w[(oc * 122 + ic) * 9 + s];
    outw[idx] = (short)f2bf(v);
}

// ---- weight repack thw ----
__global__ __launch_bounds__(256) void k_wrepack_thw(const float* __restrict__ thw,
                                                     short* __restrict__ outw) {
    int idx = blockIdx.x * 256 + threadIdx.x;
    if (idx >= 126976) return;    // 31*8*64*8
    int j    = idx & 7;
    int lane = (idx >> 3) & 63;
    int kc   = (idx >> 9) & 7;
    int g    = idx >> 12;
    int m = lane & 31, kg = lane >> 5;
    int k = kc * 16 + kg * 8 + j;
    int sel = m >> 3, mc = m & 7;
    int ch = g * 8 + mc;
    float v = 0.f;
    if (sel < 3 && ch < 244 && k < 122)
        v = thw[(sel * 244 + ch) * 122 + k];
    outw[idx] = (short)f2bf(v);
}

#define ADV11(cb, kx) { if (kx == 10) { kx = 0; cb += 384; } else { ++kx; cb += 24; } }
#define MFMA8(W0, W1, W2, W3, V0, V1) { \
    acc[0] = __builtin_amdgcn_mfma_f32_32x32x16_bf16(W0, V0, acc[0], 0, 0, 0); \
    acc[1] = __builtin_amdgcn_mfma_f32_32x32x16_bf16(W0, V1, acc[1], 0, 0, 0); \
    acc[2] = __builtin_amdgcn_mfma_f32_32x32x16_bf16(W1, V0, acc[2], 0, 0, 0); \
    acc[3] = __builtin_amdgcn_mfma_f32_32x32x16_bf16(W1, V1, acc[3], 0, 0, 0); \
    acc[4] = __builtin_amdgcn_mfma_f32_32x32x16_bf16(W2, V0, acc[4], 0, 0, 0); \
    acc[5] = __builtin_amdgcn_mfma_f32_32x32x16_bf16(W2, V1, acc[5], 0, 0, 0); \
    acc[6] = __builtin_amdgcn_mfma_f32_32x32x16_bf16(W3, V0, acc[6], 0, 0, 0); \
    acc[7] = __builtin_amdgcn_mfma_f32_32x32x16_bf16(W3, V1, acc[7], 0, 0, 0); }

// ---- MFMA 11x11 conv 121->121 v7: weights LDS-staged, double-buffered, 4-tap groups ----
__global__ __launch_bounds__(256, 2) void k_conv11_mfma(const ushortt* __restrict__ in,
                                                        const short* __restrict__ Wf,
                                                        const float* __restrict__ bias,
                                                        float scale,
                                                        const ushortt* __restrict__ cmp,
                                                        ushortt* __restrict__ out,
                                                        float* __restrict__ lossout) {
    __shared__ __align__(16) ushortt lt[26 * 26 * 24];   // 32,448 B
    __shared__ __align__(16) short8 wbuf[2][1024];       // 32,768 B
    int tid = threadIdx.x;
    int lane = tid & 63, wv = tid >> 6;
    int l15 = lane & 15, sub = (lane >> 4) & 1, kg = lane >> 5;
    int bx = blockIdx.x, b = blockIdx.y;
    int y0 = (bx >> 4) * 16, x0 = (bx & 15) * 16;
    bool interior = (y0 != 0) && (y0 != 240) && (x0 != 0) && (x0 != 240);

    floatx16 acc[8];
    #pragma unroll
    for (int i = 0; i < 8; ++i)
        #pragma unroll
        for (int e = 0; e < 16; ++e) acc[i][e] = 0.f;

    const short8* Wf8 = (const short8*)Wf;
    for (int kc = 0; kc < 8; ++kc) {
        __syncthreads();     // prev chunk's lt & wbuf reads done
        // stage input tile
        if (interior) {
            for (int pi = tid; pi < 416; pi += 256) {
                int ic = pi / 26, r = pi - ic * 26;
                int gic = kc * 16 + ic;
                ushortt* dst = &lt[r * 26 * 24 + ic];
                if (gic < 121) {
                    const ushortt* src = in + ((b * 121 + gic) << 16) + ((y0 + r - 5) << 8) + x0 - 8;
                    #pragma unroll
                    for (int sg = 0; sg < 4; ++sg) {
                        short8 v = *(const short8*)&src[sg * 8];
                        #pragma unroll
                        for (int q = 0; q < 8; ++q) {
                            int c = sg * 8 + q - 3;
                            if ((unsigned)c < 26u) dst[c * 24] = (ushortt)v[q];
                        }
                    }
                } else {
                    #pragma unroll
                    for (int c = 0; c < 26; ++c) dst[c * 24] = 0;
                }
            }
        } else {
            for (int idx = tid; idx < 26 * 26 * 16; idx += 256) {
                int ic = idx / 676, pix = idx - ic * 676;
                int r = pix / 26, c = pix - r * 26;
                int gic = kc * 16 + ic;
                ushortt v = 0;
                if (gic < 121) {
                    int gy = refl(y0 + r - 5), gx = refl(x0 + c - 5);
                    v = in[((b * 121 + gic) << 16) + (gy << 8) + gx];
                }
                lt[pix * 24 + ic] = v;
            }
        }
        // stage weight group 0
        const short8* wpg = Wf8 + kc * 124 * 256;
        short8 p0 = wpg[tid], p1 = wpg[tid + 256], p2 = wpg[tid + 512], p3 = wpg[tid + 768];
        wbuf[0][tid] = p0; wbuf[0][tid + 256] = p1;
        wbuf[0][tid + 512] = p2; wbuf[0][tid + 768] = p3;
        __syncthreads();

        int cur = 0;
        int cb = ((4 * wv + sub) * 26 + l15) * 24 + kg * 8;
        int kx = 0;
        #pragma unroll 1
        for (int g = 0; g < 31; ++g) {
            if (g < 30) {
                wpg += 1024;
                p0 = wpg[tid]; p1 = wpg[tid + 256]; p2 = wpg[tid + 512]; p3 = wpg[tid + 768];
            }
            const short8* wb = wbuf[cur];
            #pragma unroll
            for (int tt = 0; tt < 4; ++tt) {
                short8 A0 = wb[tt * 256 + lane];
                short8 A1 = wb[tt * 256 + 64 + lane];
                short8 A2 = wb[tt * 256 + 128 + lane];
                short8 A3 = wb[tt * 256 + 192 + lane];
                short8 B0 = *(const short8*)&lt[cb];
                short8 B1 = *(const short8*)&lt[cb + 1248];
                MFMA8(A0, A1, A2, A3, B0, B1);
                ADV11(cb, kx);
            }
            if (g < 30) {
                short8* wn = wbuf[cur ^ 1];
                wn[tid] = p0; wn[tid + 256] = p1; wn[tid + 512] = p2; wn[tid + 768] = p3;
            }
            __syncthreads();
            cur ^= 1;
        }
    }
    if (!cmp) {
        #pragma unroll
        for (int mt = 0; mt < 4; ++mt) {
            #pragma unroll
            for (int e = 0; e < 16; ++e) {
                int oc = mt * 32 + (e & 3) + 8 * (e >> 2) + 4 * kg;
                if (oc < 121) {
                    float bv = bias ? bias[oc] : 0.f;
                    #pragma unroll
                    for (int t = 0; t < 2; ++t) {
                        int y = y0 + 4 * wv + 2 * t + sub, x = x0 + l15;
                        out[((b * 121 + oc) << 16) + (y << 8) + x] = f2bf((acc[mt * 2 + t][e] + bv) * scale);
                    }
                }
            }
        }
    } else {
        float lsum = 0.f;
        #pragma unroll
        for (int mt = 0; mt < 4; ++mt) {
            #pragma unroll
            for (int e = 0; e < 16; ++e) {
                int oc = mt * 32 + (e & 3) + 8 * (e >> 2) + 4 * kg;
                if (oc < 121) {
                    float bv = bias ? bias[oc] : 0.f;
                    #pragma unroll
                    for (int t = 0; t < 2; ++t) {
                        int y = y0 + 4 * wv + 2 * t + sub, x = x0 + l15;
                        float res = (acc[mt * 2 + t][e] + bv) * scale;
                        float df = res - bf2f(cmp[((b * 121 + oc) << 16) + (y << 8) + x]);
                        lsum += df * df;
                    }
                }
            }
        }
        __syncthreads();
        float* red = (float*)lt;
        red[tid] = lsum;
        __syncthreads();
        for (int off = 128; off > 0; off >>= 1) {
            if (tid < off) red[tid] += red[tid + off];
            __syncthreads();
        }
        if (tid == 0) atomicAdd(lossout, red[0]);
    }
}

// ---- MFMA 3x3 conv 122->121, bf16 in/out, zero pad, sey folded, clip ----
__global__ __launch_bounds__(256, 2) void k_conv3_mfma(const ushortt* __restrict__ in,
                                                       const short* __restrict__ Wf,
                                                       const float* __restrict__ bias,
                                                       const float* __restrict__ sey,
                                                       ushortt* __restrict__ out) {
    __shared__ __align__(16) ushortt lt[18 * 18 * 24];
    int tid = threadIdx.x;
    int lane = tid & 63, wv = tid >> 6;
    int l15 = lane & 15, sub = (lane >> 4) & 1, kg = lane >> 5;
    int bx = blockIdx.x, b = blockIdx.y;
    int y0 = (bx >> 4) * 16, x0 = (bx & 15) * 16;

    floatx16 acc[8];
    #pragma unroll
    for (int i = 0; i < 8; ++i)
        #pragma unroll
        for (int e = 0; e < 16; ++e) acc[i][e] = 0.f;

    const short8* Wf8 = (const short8*)Wf;
    for (int kc = 0; kc < 8; ++kc) {
        __syncthreads();
        for (int idx = tid; idx < 18 * 18 * 16; idx += 256) {
            int ic = idx / 324, pix = idx - ic * 324;
            int r = pix / 18, c = pix - r * 18;
            int gic = kc * 16 + ic;
            float v = 0.f;
            if (gic < 122) {
                int gy = y0 + r - 1, gx = x0 + c - 1;
                if ((unsigned)gy < 256u && (unsigned)gx < 256u)
                    v = bf2f(in[((b * 122 + gic) << 16) + (gy << 8) + gx]) * sey[b * 122 + gic];
            }
            lt[pix * 24 + ic] = f2bf(v);
        }
        __syncthreads();
        const short8* wp = Wf8 + kc * 256 + lane;
        int cb = ((4 * wv + sub) * 18 + l15) * 24 + kg * 8;
        short8 a0 = wp[0], a1 = wp[64], a2 = wp[128], a3 = wp[192];
        short8 b0 = *(const short8*)&lt[cb];
        short8 b1 = *(const short8*)&lt[cb + 864];
        int kx = 0;
        #pragma unroll 1
        for (int s = 0; s < 9; ++s) {
            short8 na0 = a0, na1 = a1, na2 = a2, na3 = a3, nb0 = b0, nb1 = b1;
            if (s < 8) {
                wp += 2048;
                if (kx == 2) { kx = 0; cb += 384; }
                else         { ++kx;  cb += 24;  }
                na0 = wp[0]; na1 = wp[64]; na2 = wp[128]; na3 = wp[192];
                nb0 = *(const short8*)&lt[cb];
                nb1 = *(const short8*)&lt[cb + 864];
            }
            acc[0] = __builtin_amdgcn_mfma_f32_32x32x16_bf16(a0, b0, acc[0], 0, 0, 0);
            acc[1] = __builtin_amdgcn_mfma_f32_32x32x16_bf16(a0, b1, acc[1], 0, 0, 0);
            acc[2] = __builtin_amdgcn_mfma_f32_32x32x16_bf16(a1, b0, acc[2], 0, 0, 0);
            acc[3] = __builtin_amdgcn_mfma_f32_32x32x16_bf16(a1, b1, acc[3], 0, 0, 0);
            acc[4] = __builtin_amdgcn_mfma_f32_32x32x16_bf16(a2, b0, acc[4], 0, 0, 0);
            acc[5] = __builtin_amdgcn_mfma_f32_32x32x16_bf16(a2, b1, acc[5], 0, 0, 0);
            acc[6] = __builtin_amdgcn_mfma_f32_32x32x16_bf16(a3, b0, acc[6], 0, 0, 0);
            acc[7] = __builtin_amdgcn_mfma_f32_32x32x16_bf16(a3, b1, acc[7], 0, 0, 0);
            a0 = na0; a1 = na1; a2 = na2; a3 = na3; b0 = nb0; b1 = nb1;
        }
    }
    #pragma unroll
    for (int mt = 0; mt < 4; ++mt) {
        #pragma unroll
        for (int e = 0; e < 16; ++e) {
            int oc = mt * 32 + (e & 3) + 8 * (e >> 2) + 4 * kg;
            if (oc < 121) {
                float bv = bias[oc];
                #pragma unroll
                for (int t = 0; t < 2; ++t) {
                    int y = y0 + 4 * wv + 2 * t + sub, x = x0 + l15;
                    float res = fminf(fmaxf(acc[mt * 2 + t][e] + bv, 0.f), 10.f);
                    out[((b * 121 + oc) << 16) + (y << 8) + x] = f2bf(res);
                }
            }
        }
    }
}

// ---- FSAS: per 8x8 patch, MFMA 1x1 conv + VALU depthwise/circular; Wx bf16 ----
__global__ __launch_bounds__(256, 3) void k_fsas_patch(const float* __restrict__ input,
                                                       const ushortt* __restrict__ Wx,
                                                       const float* __restrict__ n1w,
                                                       const float* __restrict__ n1b,
                                                       const short* __restrict__ thwf,
                                                       const float* __restrict__ tdw,
                                                       ushortt* __restrict__ o_out,
                                                       ushortt* __restrict__ v_out) {
    __shared__ __align__(16) ushortt xnb[100 * 136];
    __shared__ __align__(16) float h_lds[24 * 100];
    __shared__ __align__(16) float qb[8 * 64];
    __shared__ __align__(16) float kbd[8 * 8 * 20];
    int patch = blockIdx.x, b = blockIdx.y;
    int py0 = (patch >> 5) << 3, px0 = (patch & 31) << 3;
    int tid = threadIdx.x;
    int lane = tid & 63, wvv = tid >> 6;
    int l31 = lane & 31, kg = lane >> 5;

    for (int idx = tid; idx < 12200; idx += 256) {
        int c = idx / 100, pos = idx - c * 100;
        int gy = py0 + pos / 10 - 1, gx = px0 + pos % 10 - 1;
        ushortt v = 0;
        if ((unsigned)gy < 256u && (unsigned)gx < 256u) {
            int pix = (gy << 8) + gx;
            v = (c == 0) ? f2bf(input[(b << 16) + pix]) : Wx[((b * 121 + c - 1) << 16) + pix];
        }
        xnb[pos * 136 + c] = v;
    }
    for (int idx = tid; idx < 600; idx += 256) {
        int pos = idx / 6, c = 122 + (idx - (idx / 6) * 6);
        xnb[pos * 136 + c] = 0;
    }
    __syncthreads();
    if (tid < 100) {
        int pos = tid;
        int gy = py0 + pos / 10 - 1, gx = px0 + pos % 10 - 1;
        if ((unsigned)gy < 256u && (unsigned)gx < 256u) {
            float s = 0.f, ss = 0.f;
            for (int c = 0; c < 122; ++c) { float v = bf2f(xnb[pos * 136 + c]); s += v; ss += v * v; }
            float mu = s * (1.f / 122.f);
            float rs = rsqrtf(fmaxf(ss * (1.f / 122.f) - mu * mu, 0.f) + 1e-5f);
            for (int c = 0; c < 122; ++c) {
                float v = (bf2f(xnb[pos * 136 + c]) - mu) * rs * n1w[c] + n1b[c];
                xnb[pos * 136 + c] = f2bf(v);
            }
        }
    }
    __syncthreads();

    int p = wvv * 32 + l31;
    int pe = p < 100 ? p : 0;
    short8 bfr[8];
    #pragma unroll
    for (int kc = 0; kc < 8; ++kc)
        bfr[kc] = *(const short8*)&xnb[pe * 136 + kc * 16 + kg * 8];

    const short8* Af = (const short8*)thwf;
    for (int g = 0; g < 31; ++g) {
        floatx16 acc;
        #pragma unroll
        for (int e = 0; e < 16; ++e) acc[e] = 0.f;
        #pragma unroll
        for (int kc = 0; kc < 8; ++kc) {
            short8 a = Af[(g * 8 + kc) * 64 + lane];
            acc = __builtin_amdgcn_mfma_f32_32x32x16_bf16(a, bfr[kc], acc, 0, 0, 0);
        }
        if (p < 100) {
            #pragma unroll
            for (int e = 0; e < 16; ++e) {
                int m = (e & 3) + 8 * (e >> 2) + 4 * kg;
                if (m < 24) h_lds[m * 100 + p] = acc[e];
            }
        }
        __syncthreads();
        for (int it = tid; it < 1536; it += 256) {
            int m = it >> 6, pp = it & 63;
            int sel = m >> 3, cl = m & 7;
            int ch = g * 8 + cl;
            int py = pp >> 3, px = pp & 7;
            float dv = 0.f;
            if (ch < 244) {
                const float* td = tdw + (sel * 244 + ch) * 9;
                const float* hrow = &h_lds[m * 100];
                #pragma unroll
                for (int dy = 0; dy < 3; ++dy)
                    #pragma unroll
                    for (int dx = 0; dx < 3; ++dx)
                        dv += td[dy * 3 + dx] * hrow[(py + dy) * 10 + px + dx];
            }
            if (sel == 0) qb[cl * 64 + pp] = dv;
            else if (sel == 1) {
                kbd[(cl * 8 + py) * 20 + px] = dv;
                kbd[(cl * 8 + py) * 20 + px + 8] = dv;
            } else if (ch < 244) {
                v_out[((b * 244 + ch) << 16) + ((py0 + py) << 8) + px0 + px] = f2bf(dv);
            }
        }
        __syncthreads();
        {
            int cl = tid >> 5, u = (tid >> 2) & 7, ih = tid & 3;
            float ov[8];
            #pragma unroll
            for (int v = 0; v < 8; ++v) ov[v] = 0.f;
            #pragma unroll
            for (int ii = 0; ii < 2; ++ii) {
                int i = ih * 2 + ii;
                const float* qr = &qb[cl * 64 + i * 8];
                float q[8];
                *(float4*)q       = *(const float4*)qr;
                *(float4*)(q + 4) = *(const float4*)(qr + 4);
                const float* kr = &kbd[(cl * 8 + ((u - i) & 7)) * 20];
                float kk[16];
                *(float4*)kk        = *(const float4*)kr;
                *(float4*)(kk + 4)  = *(const float4*)(kr + 4);
                *(float4*)(kk + 8)  = *(const float4*)(kr + 8);
                *(float4*)(kk + 12) = *(const float4*)(kr + 12);
                #pragma unroll
                for (int j = 0; j < 8; ++j)
                    #pragma unroll
                    for (int v = 0; v < 8; ++v)
                        ov[v] += q[j] * kk[v + 8 - j];
            }
            #pragma unroll
            for (int v = 0; v < 8; ++v) {
                ov[v] += __shfl_xor(ov[v], 1);
                ov[v] += __shfl_xor(ov[v], 2);
            }
            int ch = g * 8 + cl;
            if (ih == 0 && ch < 244) {
                uint4 pk;
                pk.x = (unsigned)f2bf(ov[0]) | ((unsigned)f2bf(ov[1]) << 16);
                pk.y = (unsigned)f2bf(ov[2]) | ((unsigned)f2bf(ov[3]) << 16);
                pk.z = (unsigned)f2bf(ov[4]) | ((unsigned)f2bf(ov[5]) << 16);
                pk.w = (unsigned)f2bf(ov[6]) | ((unsigned)f2bf(ov[7]) << 16);
                *(uint4*)&o_out[((size_t)((b * 244 + ch)) << 16) + ((py0 + u) << 8) + px0] = pk;
            }
        }
        __syncthreads();
    }
}

// ---- a = v * LN_c(o) (in place over v), 8 px/thread ----
__global__ __launch_bounds__(256) void k_a_ln(const ushortt* __restrict__ o,
                                              ushortt* __restrict__ v,
                                              const float* __restrict__ fnw,
                                              const float* __restrict__ fnb) {
    int t = blockIdx.x * 256 + threadIdx.x;
    int p8 = t * 8;
    int b = p8 >> 16, pix = p8 & 65535;
    float s[8], ss[8];
    #pragma unroll
    for (int q = 0; q < 8; ++q) { s[q] = 0.f; ss[q] = 0.f; }
    for (int c = 0; c < 244; ++c) {
        short8 o8 = *(const short8*)&o[((b * 244 + c) << 16) + pix];
        #pragma unroll
        for (int q = 0; q < 8; ++q) {
            float f = bf2f_s(o8[q]);
            s[q] += f; ss[q] += f * f;
        }
    }
    float mu[8], rs[8];
    #pragma unroll
    for (int q = 0; q < 8; ++q) {
        mu[q] = s[q] * (1.f / 244.f);
        rs[q] = rsqrtf(fmaxf(ss[q] * (1.f / 244.f) - mu[q] * mu[q], 0.f) + 1e-5f);
    }
    for (int c = 0; c < 244; ++c) {
        int base = ((b * 244 + c) << 16) + pix;
        short8 o8 = *(const short8*)&o[base];
        short8 v8 = *(const short8*)&v[base];
        float w = fnw[c], bb = fnb[c];
        short8 r8;
        #pragma unroll
        for (int q = 0; q < 8; ++q) {
            float tt = (bf2f_s(o8[q]) - mu[q]) * rs[q] * w + bb;
            r8[q] = (short)f2bf(bf2f_s(v8[q]) * tt);
        }
        *(short8*)&v[base] = r8;
    }
}

// ---- out1(bf16) = cat + pw(1x1) @ a ; 8 px x 8 oc/thread, pw in LDS; Wx bf16 ----
__global__ __launch_bounds__(256) void k_pw_res(const ushortt* __restrict__ a,
                                                const float* __restrict__ pw,
                                                const float* __restrict__ input,
                                                const ushortt* __restrict__ Wx,
                                                ushortt* __restrict__ out1) {
    __shared__ float pws[8 * 244];
    int g = blockIdx.y, b = blockIdx.z;
    int tid = threadIdx.x;
    for (int i = tid; i < 8 * 244; i += 256) {
        int j = i / 244, c = i - j * 244;
        int oc = g * 8 + j;
        pws[i] = (oc < 122) ? pw[oc * 244 + c] : 0.f;
    }
    __syncthreads();
    int p = (blockIdx.x * 256 + tid) * 8;
    float acc[8][8];
    #pragma unroll
    for (int j = 0; j < 8; ++j)
        #pragma unroll
        for (int q = 0; q < 8; ++q) acc[j][q] = 0.f;
    for (int c = 0; c < 244; ++c) {
        short8 a8 = *(const short8*)&a[((b * 244 + c) << 16) + p];
        float av[8];
        #pragma unroll
        for (int q = 0; q < 8; ++q) av[q] = bf2f_s(a8[q]);
        #pragma unroll
        for (int j = 0; j < 8; ++j) {
            float w = pws[j * 244 + c];
            #pragma unroll
            for (int q = 0; q < 8; ++q) acc[j][q] += w * av[q];
        }
    }
    #pragma unroll
    for (int j = 0; j < 8; ++j) {
        int oc = g * 8 + j;
        if (oc < 122) {
            float cat[8];
            if (oc == 0) {
                const float* src = input + (b << 16) + p;
                float4 c0 = *(const float4*)src;
                float4 c1 = *(const float4*)(src + 4);
                cat[0] = c0.x; cat[1] = c0.y; cat[2] = c0.z; cat[3] = c0.w;
                cat[4] = c1.x; cat[5] = c1.y; cat[6] = c1.z; cat[7] = c1.w;
            } else {
                short8 w8 = *(const short8*)&Wx[((b * 121 + oc - 1) << 16) + p];
                #pragma unroll
                for (int q = 0; q < 8; ++q) cat[q] = bf2f_s(w8[q]);
            }
            short8 r8;
            #pragma unroll
            for (int q = 0; q < 8; ++q) r8[q] = (short)f2bf(cat[q] + acc[j][q]);
            *(short8*)&out1[((b * 122 + oc) << 16) + p] = r8;
        }
    }
}

// ---- SE: channel means (bf16 input) ----
__global__ __launch_bounds__(256) void k_se_mean(const ushortt* __restrict__ x, float* __restrict__ mean) {
    int c = blockIdx.x, b = blockIdx.y;
    const ushortt* p = x + ((b * 122 + c) << 16);
    float s = 0.f;
    for (int i = threadIdx.x * 8; i < HW; i += 2048) {
        short8 v8 = *(const short8*)&p[i];
        #pragma unroll
        for (int q = 0; q < 8; ++q) s += bf2f_s(v8[q]);
    }
    __shared__ float red[256];
    red[threadIdx.x] = s;
    __syncthreads();
    for (int off = 128; off > 0; off >>= 1) {
        if (threadIdx.x < off) red[threadIdx.x] += red[threadIdx.x + off];
        __syncthreads();
    }
    if (threadIdx.x == 0) mean[b * 122 + c] = red[0] * (1.f / HW);
}

// ---- SE: fc -> relu -> fc -> sigmoid ----
__global__ __launch_bounds__(256) void k_se_fc(const float* __restrict__ mean,
                                               const float* __restrict__ f1,
                                               const float* __restrict__ f2,
                                               float* __restrict__ sey) {
    int b = blockIdx.x, tid = threadIdx.x;
    __shared__ float y1[7];
    if (tid < 7) {
        float s = 0.f;
        for (int c = 0; c < 122; ++c) s += f1[tid * 122 + c] * mean[b * 122 + c];
        y1[tid] = fmaxf(s, 0.f);
    }
    __syncthreads();
    if (tid < 122) {
        float s = 0.f;
        #pragma unroll
        for (int j = 0; j < 7; ++j) s += f2[tid * 7 + j] * y1[j];
        sey[b * 122 + tid] = 1.f / (1.f + expf(-s));
    }
}

// ---- z(bf16) = soft(Wx(bf16), c*sigma), 8 px/thread ----
__global__ __launch_bounds__(256) void k_soft(const ushortt* __restrict__ Wx,
                                              const ushortt* __restrict__ cbuf,
                                              const float* __restrict__ sigma,
                                              ushortt* __restrict__ z) {
    int idx = (blockIdx.x * 256 + threadIdx.x) * 8;
    int pix = idx & 65535;
    int b = (idx >> 16) / 121;
    short8 x8 = *(const short8*)&Wx[idx];
    short8 c8 = *(const short8*)&cbuf[idx];
    const float* sp = &sigma[(b << 16) + pix];
    float4 s0 = *(const float4*)sp;
    float4 s1 = *(const float4*)(sp + 4);
    float sv[8] = {s0.x, s0.y, s0.z, s0.w, s1.x, s1.y, s1.z, s1.w};
    short8 r8;
    #pragma unroll
    for (int q = 0; q < 8; ++q) {
        float t = bf2f_s(c8[q]) * sv[q];
        float x = bf2f_s(x8[q]);
        float r = x > t ? x - t : (x < -t ? x + t : 0.f);
        r8[q] = (short)f2bf(r);
    }
    *(short8*)&z[idx] = r8;
}

// ---- Wt = conv11(Wt2(bf16), rot180(w1)^T)/121, 121 -> 1; tile stride 48 ----
__global__ __launch_bounds__(256) void k_wt(const ushortt* __restrict__ Wt2,
                                            const float* __restrict__ w1,
                                            float* __restrict__ out) {
    __shared__ float tile[26 * 48];
    int b = blockIdx.y;
    int ty0 = (blockIdx.x >> 4) * 16, tx0 = (blockIdx.x & 15) * 16;
    int tid = threadIdx.x;
    int tX = tid & 15, tY = tid >> 4;
    float acc = 0.f;
    for (int ic = 0; ic < 121; ++ic) {
        const ushortt* src = Wt2 + ((b * 121 + ic) << 16);
        for (int idx = tid; idx < 26 * 26; idx += 256) {
            int r = idx / 26, c = idx - r * 26;
            tile[r * 48 + c] = bf2f(src[(refl(ty0 + r - 5) << 8) + refl(tx0 + c - 5)]);
        }
        __syncthreads();
        const float* wr = w1 + ic * 121;
        #pragma unroll 1
        for (int ky = 0; ky < 11; ++ky) {
            #pragma unroll
            for (int kx = 0; kx < 11; ++kx)
                acc += wr[(10 - ky) * 11 + (10 - kx)] * tile[(tY + ky) * 48 + tX + kx];
        }
        __syncthreads();
    }
    out[(b << 16) + ((ty0 + tY) << 8) + tx0 + tX] = acc * (1.f / 121.f);
}

extern "C" void kernel_launch(void* const* d_in, const int* in_sizes, int n_in,
                              void* d_out, int out_size, void* d_ws, size_t ws_size,
                              hipStream_t stream) {
    const float* input = (const float*)d_in[0];
    const float* sigma = (const float*)d_in[1];
    const float* w1    = (const float*)d_in[2];
    const float* b1    = (const float*)d_in[3];
    const float* w2    = (const float*)d_in[4];
    const float* b2    = (const float*)d_in[5];
    const float* n1w   = (const float*)d_in[6];
    const float* n1b   = (const float*)d_in[7];
    const float* thw   = (const float*)d_in[8];
    const float* tdw   = (const float*)d_in[9];
    const float* fnw   = (const float*)d_in[10];
    const float* fnb   = (const float*)d_in[11];
    const float* pw    = (const float*)d_in[12];
    const float* se1f1 = (const float*)d_in[13];
    const float* se1f2 = (const float*)d_in[14];
    const float* se2f1 = (const float*)d_in[15];
    const float* se2f2 = (const float*)d_in[16];
    const float* c1w   = (const float*)d_in[17];
    const float* c1b   = (const float*)d_in[18];
    const float* c2w   = (const float*)d_in[19];
    const float* c2b   = (const float*)d_in[20];
    float* out = (float*)d_out;
    float* ws  = (float*)d_ws;

    const size_t T121 = 15859712, T122 = 15990784;
    float* Wx1f   = ws;
    float* bufBf  = Wx1f + T121;
    float* C      = bufBf + T121;
    float* D      = C + T122;
    float* means  = D + T122;
    float* sey    = means + 256;
    short* thwf   = (short*)(sey + 256);
    ushortt* Wx1   = (ushortt*)Wx1f;
    ushortt* bufB  = (ushortt*)bufBf;
    ushortt* o_bf  = (ushortt*)C;
    ushortt* out1_bf = (ushortt*)C;
    ushortt* z_bf  = (ushortt*)C;
    ushortt* temp_bf = (ushortt*)C;
    ushortt* v_bf  = (ushortt*)D;
    ushortt* c_bf  = (ushortt*)D;
    short* WfA = (short*)D;                      // 4.06 MB
    short* WfB = (short*)(D + (1 << 20));        // 4 MB offset (WfA = 4.06 MB <= 4.19 MB gap... use 1.1M)
    short* Wf3 = (short*)(D + 9000000);
    WfB = (short*)(D + 1100000);                 // 4.4 MB offset, safe for 4.06 MB WfA

    dim3 blk(256);
    const ushortt* UNUL = nullptr;
    float* FNUL = nullptr;

    k_init<<<dim3(58), blk, 0, stream>>>(w1, out);
    k_wrepack_thw<<<dim3(496), blk, 0, stream>>>(thw, thwf);
    k_conv11_1toC<<<dim3(256, 121, 2), blk, 0, stream>>>(input, w1, b1, Wx1);

    // ---- tblock 1 ----
    k_fsas_patch<<<dim3(1024, 2), blk, 0, stream>>>(input, Wx1, n1w, n1b, thwf, tdw, o_bf, v_bf);
    k_a_ln<<<dim3(64), blk, 0, stream>>>(o_bf, v_bf, fnw, fnb);
    k_pw_res<<<dim3(32, 16, 2), blk, 0, stream>>>(v_bf, pw, input, Wx1, out1_bf);    // out1 -> C
    k_wrepack3<<<dim3(576), blk, 0, stream>>>(c1w, Wf3);
    k_se_mean<<<dim3(122, 2), blk, 0, stream>>>(out1_bf, means);
    k_se_fc<<<dim3(2), blk, 0, stream>>>(means, se1f1, se1f2, sey);
    k_conv3_mfma<<<dim3(256, 2), blk, 0, stream>>>(out1_bf, Wf3, c1b, sey, c_bf);    // c1 -> D
    k_soft<<<dim3(7744), blk, 0, stream>>>(Wx1, c_bf, sigma, z_bf);                  // z1 -> C
    k_wrepack<<<dim3(7936), blk, 0, stream>>>(w2, 0, WfA);
    k_conv11_mfma<<<dim3(256, 2), blk, 0, stream>>>(z_bf, WfA, b2, 1.f, UNUL, bufB, FNUL); // Wx2

    // ---- tblock 2 ----
    k_fsas_patch<<<dim3(1024, 2), blk, 0, stream>>>(input, bufB, n1w, n1b, thwf, tdw, o_bf, v_bf);
    k_a_ln<<<dim3(64), blk, 0, stream>>>(o_bf, v_bf, fnw, fnb);
    k_pw_res<<<dim3(32, 16, 2), blk, 0, stream>>>(v_bf, pw, input, bufB, out1_bf);
    k_wrepack3<<<dim3(576), blk, 0, stream>>>(c2w, Wf3);
    k_se_mean<<<dim3(122, 2), blk, 0, stream>>>(out1_bf, means);
    k_se_fc<<<dim3(2), blk, 0, stream>>>(means, se2f1, se2f2, sey);
    k_conv3_mfma<<<dim3(256, 2), blk, 0, stream>>>(out1_bf, Wf3, c2b, sey, c_bf);
    k_soft<<<dim3(7744), blk, 0, stream>>>(bufB, c_bf, sigma, z_bf);                 // z2 -> C

    // ---- tail ----
    k_wrepack<<<dim3(7936), blk, 0, stream>>>(w2, 0, WfA);
    k_wrepack<<<dim3(7936), blk, 0, stream>>>(w2, 1, WfB);
    k_conv11_mfma<<<dim3(256, 2), blk, 0, stream>>>(z_bf, WfB, FNUL, 1.f / 121.f, UNUL, bufB, FNUL); // Wt2
    k_wt<<<dim3(256, 2), blk, 0, stream>>>(bufB, w1, out);                                           // Wt
    k_conv11_mfma<<<dim3(256, 2), blk, 0, stream>>>(Wx1, WfA, b2, 1.f, UNUL, temp_bf, FNUL);         // temp
    k_conv11_mfma<<<dim3(256, 2), blk, 0, stream>>>(temp_bf, WfB, FNUL, 1.f / 121.f, Wx1, (ushortt*)FNUL, out + 145713); // W2loss

    (void)in_sizes; (void)n_in; (void)out_size; (void)ws_size;
}